// Round 1
// 2092.828 us; speedup vs baseline: 1.2512x; 1.2512x over previous
//
#include <hip/hip_runtime.h>
#include <hip/hip_bf16.h>
#include <cstdint>

typedef __bf16 bf16_t;
typedef __attribute__((ext_vector_type(8))) __bf16 bf16x8;
typedef __attribute__((ext_vector_type(4))) float f32x4;

#define S_LEN 2048
#define NHEADS 16
#define DK 64
#define DMODEL 1024
#define BATCH 4
#define MROWS (BATCH * S_LEN)   // 8192

__device__ __forceinline__ bf16x8 ld8(const bf16_t* p) { return *(const bf16x8*)p; }

__device__ __forceinline__ bf16x8 cvt8(const float* p) {
    f32x4 a = *(const f32x4*)p;
    f32x4 b = *(const f32x4*)(p + 4);
    bf16x8 r;
    r[0] = (bf16_t)a[0]; r[1] = (bf16_t)a[1]; r[2] = (bf16_t)a[2]; r[3] = (bf16_t)a[3];
    r[4] = (bf16_t)b[0]; r[5] = (bf16_t)b[1]; r[6] = (bf16_t)b[2]; r[7] = (bf16_t)b[3];
    return r;
}

// async global->LDS, 16B per lane; lds pointer must be wave-uniform (HW adds lane*16)
__device__ __forceinline__ void gl_lds16(const bf16_t* g, bf16_t* l) {
    __builtin_amdgcn_global_load_lds(
        (const __attribute__((address_space(1))) uint32_t*)g,
        (__attribute__((address_space(3))) uint32_t*)l, 16, 0, 0);
}

// ---------------- fp32 -> bf16 convert ----------------
__global__ __launch_bounds__(256) void cvt_kernel(const float* __restrict__ in,
                                                  bf16_t* __restrict__ out) {
    int i = (blockIdx.x * 256 + threadIdx.x) * 8;
    *(bf16x8*)(out + i) = cvt8(in + i);
}

// ---------------- mask bit-pack ----------------
__global__ __launch_bounds__(256) void pack_mask_kernel(const int* __restrict__ mask,
                                                        unsigned long long* __restrict__ bits) {
    size_t idx = (size_t)blockIdx.x * 256 + threadIdx.x;
    int v = mask[idx];
    unsigned long long b = __ballot(v != 0);
    if ((threadIdx.x & 63) == 0) bits[idx >> 6] = b;
}

// ---------------- LDS-staged GEMM: Y = X @ W^T + bias ----------------
// X: (8192,1024) bf16, W: (1024,1024) bf16 [N][K].  128x128 tile, BK=32, dbuf LDS,
// global_load_lds width-16 staging (m97 structure).
// mode 0: (B,H,S,64)  mode 1: (B,H,64,S)  mode 2: (M,1024)
__global__ __launch_bounds__(256) void gemm_bt(
    const bf16_t* __restrict__ X, const bf16_t* __restrict__ W,
    const float* __restrict__ bias, bf16_t* __restrict__ Y, int mode)
{
    __shared__ bf16_t As[2][128 * 32];
    __shared__ bf16_t Bs[2][128 * 32];
    const int K = DMODEL;
    int lane = threadIdx.x & 63;
    int wave = threadIdx.x >> 6;
    int lr = lane & 15, lg = lane >> 4;
    int wr = wave >> 1, wc = wave & 1;          // 2x2 wave grid, 64x64 per wave
    int i0 = blockIdx.x * 128;
    int j0 = blockIdx.y * 128;

    // staging: round r, wave w covers LDS rows [r*64 + w*16 + lane/4], cols (lane&3)*8
    const bf16_t* xg = X + (size_t)(i0 + wave * 16 + (lane >> 2)) * K + (lane & 3) * 8;
    const bf16_t* wg = W + (size_t)(j0 + wave * 16 + (lane >> 2)) * K + (lane & 3) * 8;

    f32x4 acc[4][4] = {};

    auto stage = [&](int buf, int k0) {
        #pragma unroll
        for (int r = 0; r < 2; ++r) {
            gl_lds16(xg + (size_t)(r * 64) * K + k0, &As[buf][r * 2048 + wave * 512]);
            gl_lds16(wg + (size_t)(r * 64) * K + k0, &Bs[buf][r * 2048 + wave * 512]);
        }
    };

    stage(0, 0);
    for (int t = 0; t < K / 32; ++t) {
        __syncthreads();                         // drains vmcnt: buf (t&1) ready
        if (t + 1 < K / 32) stage((t + 1) & 1, (t + 1) * 32);
        const bf16_t* ab = &As[t & 1][(wr * 64 + lr) * 32 + lg * 8];
        const bf16_t* bb = &Bs[t & 1][(wc * 64 + lr) * 32 + lg * 8];
        bf16x8 a[4], b[4];
        #pragma unroll
        for (int m = 0; m < 4; ++m) a[m] = ld8(ab + m * 16 * 32);
        #pragma unroll
        for (int n = 0; n < 4; ++n) b[n] = ld8(bb + n * 16 * 32);
        __builtin_amdgcn_s_setprio(1);
        #pragma unroll
        for (int m = 0; m < 4; ++m)
            #pragma unroll
            for (int n = 0; n < 4; ++n)
                acc[m][n] = __builtin_amdgcn_mfma_f32_16x16x32_bf16(a[m], b[n], acc[m][n], 0, 0, 0);
        __builtin_amdgcn_s_setprio(0);
    }

    #pragma unroll
    for (int n = 0; n < 4; ++n) {
        int col = j0 + wc * 64 + n * 16 + lr;
        float bv = bias[col];
        #pragma unroll
        for (int m = 0; m < 4; ++m) {
            #pragma unroll
            for (int r = 0; r < 4; ++r) {
                int row = i0 + wr * 64 + m * 16 + lg * 4 + r;  // C/D: col=lane&15, row=(lane>>4)*4+reg
                float v = acc[m][n][r] + bv;
                size_t off;
                if (mode == 2) {
                    off = (size_t)row * DMODEL + col;
                } else {
                    int b = row >> 11, s = row & (S_LEN - 1);
                    int h = col >> 6, d = col & (DK - 1);
                    if (mode == 0) off = ((size_t)(b * NHEADS + h) * S_LEN + s) * DK + d;
                    else           off = ((size_t)(b * NHEADS + h) * DK + d) * S_LEN + s;
                }
                Y[off] = (bf16_t)v;
            }
        }
    }
}

// ---------------- fused attention ----------------
// psharef is wave-private -> NO __syncthreads anywhere (intra-wave LDS deps are
// handled by compiler-inserted lgkmcnt waits). Waves run fully decoupled.
__global__ __launch_bounds__(256) void attn_kernel(
    const bf16_t* __restrict__ qb, const bf16_t* __restrict__ kb,
    const bf16_t* __restrict__ vT, const unsigned long long* __restrict__ mbits,
    float* __restrict__ attn_out, bf16_t* __restrict__ ctx_out)
{
    __shared__ __align__(16) float psharef[4][16][68];
    int lane = threadIdx.x & 63;
    int wave = threadIdx.x >> 6;
    int lr = lane & 15, lg = lane >> 4;
    int bh = blockIdx.x >> 5;
    int b = bh >> 4, h = bh & (NHEADS - 1);
    int q0 = (blockIdx.x & 31) * 64 + wave * 16;

    const bf16_t* qp = qb + ((size_t)bh * S_LEN + q0 + lr) * DK + lg * 8;
    bf16x8 aq0 = ld8(qp), aq1 = ld8(qp + 32);

    const bf16_t* kp = kb + ((size_t)bh * S_LEN + lr) * DK + lg * 8;
    const unsigned long long* mp = mbits + ((size_t)b * S_LEN + q0 + lg * 4) * (S_LEN / 64);

    float m[4] = {-1e30f, -1e30f, -1e30f, -1e30f};
    float l[4] = {0.f, 0.f, 0.f, 0.f};

    // ---- pass 1: online row max + exp-sum ----
    for (int n0 = 0; n0 < S_LEN; n0 += 64) {
        f32x4 sc[4];
        __builtin_amdgcn_s_setprio(1);
        #pragma unroll
        for (int nt = 0; nt < 4; ++nt) {
            const bf16_t* kr = kp + (size_t)(n0 + nt * 16) * DK;
            f32x4 c = {0.f, 0.f, 0.f, 0.f};
            c = __builtin_amdgcn_mfma_f32_16x16x32_bf16(aq0, ld8(kr), c, 0, 0, 0);
            c = __builtin_amdgcn_mfma_f32_16x16x32_bf16(aq1, ld8(kr + 32), c, 0, 0, 0);
            sc[nt] = c;
        }
        __builtin_amdgcn_s_setprio(0);
        int w = n0 >> 6;
        #pragma unroll
        for (int r = 0; r < 4; ++r) {
            unsigned long long mw = mp[r * (S_LEN / 64) + w];
            float sv[4];
            float mx = -1e30f;
            #pragma unroll
            for (int nt = 0; nt < 4; ++nt) {
                float s = sc[nt][r] * 0.125f;
                if (!((mw >> (nt * 16 + lr)) & 1ULL)) s = -1e9f;
                sv[nt] = s;
                mx = fmaxf(mx, s);
            }
            #pragma unroll
            for (int off = 1; off < 16; off <<= 1) mx = fmaxf(mx, __shfl_xor(mx, off, 64));
            float mn = fmaxf(m[r], mx);
            float sum = 0.f;
            #pragma unroll
            for (int nt = 0; nt < 4; ++nt) sum += __expf(sv[nt] - mn);
            #pragma unroll
            for (int off = 1; off < 16; off <<= 1) sum += __shfl_xor(sum, off, 64);
            l[r] = l[r] * __expf(m[r] - mn) + sum;
            m[r] = mn;
        }
    }
    float inv_l[4];
    #pragma unroll
    for (int r = 0; r < 4; ++r) inv_l[r] = 1.f / l[r];

    // ---- pass 2: recompute scores, write normalized attn, accumulate P@V ----
    f32x4 ctx[4] = {};
    size_t attn_base = ((size_t)bh * S_LEN + q0) * S_LEN;
    for (int n0 = 0; n0 < S_LEN; n0 += 64) {
        int w = n0 >> 6;
        #pragma unroll
        for (int nt = 0; nt < 4; ++nt) {
            const bf16_t* kr = kp + (size_t)(n0 + nt * 16) * DK;
            f32x4 c = {0.f, 0.f, 0.f, 0.f};
            __builtin_amdgcn_s_setprio(1);
            c = __builtin_amdgcn_mfma_f32_16x16x32_bf16(aq0, ld8(kr), c, 0, 0, 0);
            c = __builtin_amdgcn_mfma_f32_16x16x32_bf16(aq1, ld8(kr + 32), c, 0, 0, 0);
            __builtin_amdgcn_s_setprio(0);
            #pragma unroll
            for (int r = 0; r < 4; ++r) {
                unsigned long long mw = mp[r * (S_LEN / 64) + w];
                float s = c[r] * 0.125f;
                if (!((mw >> (nt * 16 + lr)) & 1ULL)) s = -1e9f;
                float p = __expf(s - m[r]) * inv_l[r];
                psharef[wave][lg * 4 + r][nt * 16 + lr] = p;
            }
        }
        // coalesced fp32 attn store: 4 full rows per float4-instruction (same-wave LDS dep)
        #pragma unroll
        for (int j = 0; j < 4; ++j) {
            int flat = j * 64 + lane;
            int rr = flat >> 4, cc = (flat & 15) * 4;
            *(f32x4*)(attn_out + attn_base + (size_t)rr * S_LEN + n0 + cc) =
                *(const f32x4*)&psharef[wave][rr][cc];
        }
        // PV: A-operand (P -> bf16) from wave-private LDS, B from vT
        #pragma unroll
        for (int t = 0; t < 2; ++t) {
            bf16x8 ap = cvt8(&psharef[wave][lr][t * 32 + lg * 8]);
            __builtin_amdgcn_s_setprio(1);
            #pragma unroll
            for (int dt = 0; dt < 4; ++dt) {
                const bf16_t* vr = vT + ((size_t)bh * DK + dt * 16 + lr) * S_LEN + n0 + t * 32 + lg * 8;
                ctx[dt] = __builtin_amdgcn_mfma_f32_16x16x32_bf16(ap, ld8(vr), ctx[dt], 0, 0, 0);
            }
            __builtin_amdgcn_s_setprio(0);
        }
    }
    #pragma unroll
    for (int dt = 0; dt < 4; ++dt) {
        #pragma unroll
        for (int r = 0; r < 4; ++r) {
            size_t row = (size_t)b * S_LEN + q0 + lg * 4 + r;
            int col = h * DK + dt * 16 + lr;
            ctx_out[row * DMODEL + col] = (bf16_t)ctx[dt][r];
        }
    }
}

// ---------------- residual + LayerNorm ----------------
__global__ __launch_bounds__(256) void ln_kernel(
    const bf16_t* __restrict__ proj, const float* __restrict__ Qres,
    const float* __restrict__ gamma, const float* __restrict__ beta,
    float* __restrict__ y)
{
    __shared__ float red[8];
    int row = blockIdx.x;
    int tid = threadIdx.x;
    int lane = tid & 63, wave = tid >> 6;
    const bf16_t* pr = proj + (size_t)row * DMODEL;
    const float*  qr = Qres + (size_t)row * DMODEL;
    float x[4];
    float sum = 0.f, sumsq = 0.f;
    #pragma unroll
    for (int i = 0; i < 4; ++i) {
        int c = tid + i * 256;
        float v = (float)pr[c] + qr[c];
        x[i] = v; sum += v; sumsq += v * v;
    }
    #pragma unroll
    for (int off = 1; off < 64; off <<= 1) {
        sum += __shfl_xor(sum, off, 64);
        sumsq += __shfl_xor(sumsq, off, 64);
    }
    if (lane == 0) { red[wave] = sum; red[4 + wave] = sumsq; }
    __syncthreads();
    sum = red[0] + red[1] + red[2] + red[3];
    sumsq = red[4] + red[5] + red[6] + red[7];
    float mu = sum * (1.f / DMODEL);
    float var = sumsq * (1.f / DMODEL) - mu * mu;
    float rstd = rsqrtf(var + 1e-5f);
    #pragma unroll
    for (int i = 0; i < 4; ++i) {
        int c = tid + i * 256;
        y[(size_t)row * DMODEL + c] = (x[i] - mu) * rstd * gamma[c] + beta[c];
    }
}

extern "C" void kernel_launch(void* const* d_in, const int* in_sizes, int n_in,
                              void* d_out, int out_size, void* d_ws, size_t ws_size,
                              hipStream_t stream) {
    (void)in_sizes; (void)n_in; (void)out_size; (void)ws_size;
    const float* Q   = (const float*)d_in[0];
    const float* Kin = (const float*)d_in[1];
    const float* Vin = (const float*)d_in[2];
    const int*   mask= (const int*)d_in[3];
    const float* Wq  = (const float*)d_in[4];
    const float* bq  = (const float*)d_in[5];
    const float* Wk  = (const float*)d_in[6];
    const float* bk  = (const float*)d_in[7];
    const float* Wv  = (const float*)d_in[8];
    const float* bv  = (const float*)d_in[9];
    const float* Wo  = (const float*)d_in[10];
    const float* bo  = (const float*)d_in[11];
    const float* lng = (const float*)d_in[12];
    const float* lnb = (const float*)d_in[13];

    const size_t NE = (size_t)BATCH * S_LEN * DMODEL;   // 8,388,608
    const size_t WN = (size_t)DMODEL * DMODEL;          // 1,048,576
    bf16_t* wqb  = (bf16_t*)d_ws;          // 4 converted weights (bf16)
    bf16_t* wkb  = wqb + WN;
    bf16_t* wvb  = wkb + WN;
    bf16_t* wob  = wvb + WN;
    bf16_t* qbuf = wob + WN;               // (B,H,S,64)
    bf16_t* kbuf = qbuf + NE;              // (B,H,S,64)
    bf16_t* vtbuf= kbuf + NE;              // (B,H,64,S)
    bf16_t* ctxbuf = vtbuf + NE;           // (B,S,1024)
    bf16_t* outbuf = qbuf;                 // reuse: qbuf dead after attn
    unsigned long long* mbits = (unsigned long long*)(ctxbuf + NE);  // (B,S,S/64)
    bf16_t* x16 = (bf16_t*)(mbits + (size_t)BATCH * S_LEN * (S_LEN / 64)); // reused bf16 input

    float* y_out    = (float*)d_out;
    float* attn_out = y_out + NE;

    cvt_kernel<<<WN / 2048, 256, 0, stream>>>(Wq, wqb);
    cvt_kernel<<<WN / 2048, 256, 0, stream>>>(Wk, wkb);
    cvt_kernel<<<WN / 2048, 256, 0, stream>>>(Wv, wvb);
    cvt_kernel<<<WN / 2048, 256, 0, stream>>>(Wo, wob);

    const int mask_elems = BATCH * S_LEN * S_LEN;       // 16,777,216
    pack_mask_kernel<<<mask_elems / 256, 256, 0, stream>>>(mask, mbits);

    dim3 gg(MROWS / 128, DMODEL / 128);                 // (64, 8)
    cvt_kernel<<<NE / 2048, 256, 0, stream>>>(Q, x16);
    gemm_bt<<<gg, 256, 0, stream>>>(x16, wqb, bq, qbuf, 0);
    cvt_kernel<<<NE / 2048, 256, 0, stream>>>(Kin, x16);
    gemm_bt<<<gg, 256, 0, stream>>>(x16, wkb, bk, kbuf, 0);
    cvt_kernel<<<NE / 2048, 256, 0, stream>>>(Vin, x16);
    gemm_bt<<<gg, 256, 0, stream>>>(x16, wvb, bv, vtbuf, 1);

    attn_kernel<<<BATCH * NHEADS * (S_LEN / 64), 256, 0, stream>>>(
        qbuf, kbuf, vtbuf, mbits, attn_out, ctxbuf);

    gemm_bt<<<gg, 256, 0, stream>>>(ctxbuf, wob, bo, outbuf, 2);

    ln_kernel<<<BATCH * S_LEN, 256, 0, stream>>>(outbuf, Q, lng, lnb, y_out);
}

// Round 2
// 2069.849 us; speedup vs baseline: 1.2650x; 1.0111x over previous
//
#include <hip/hip_runtime.h>
#include <hip/hip_bf16.h>
#include <cstdint>

typedef __bf16 bf16_t;
typedef __attribute__((ext_vector_type(8))) __bf16 bf16x8;
typedef __attribute__((ext_vector_type(4))) float f32x4;

#define S_LEN 2048
#define NHEADS 16
#define DK 64
#define DMODEL 1024
#define BATCH 4
#define MROWS (BATCH * S_LEN)   // 8192

__device__ __forceinline__ bf16x8 ld8(const bf16_t* p) { return *(const bf16x8*)p; }

__device__ __forceinline__ bf16x8 cvt8(const float* p) {
    f32x4 a = *(const f32x4*)p;
    f32x4 b = *(const f32x4*)(p + 4);
    bf16x8 r;
    r[0] = (bf16_t)a[0]; r[1] = (bf16_t)a[1]; r[2] = (bf16_t)a[2]; r[3] = (bf16_t)a[3];
    r[4] = (bf16_t)b[0]; r[5] = (bf16_t)b[1]; r[6] = (bf16_t)b[2]; r[7] = (bf16_t)b[3];
    return r;
}

__device__ __forceinline__ void gl_lds16(const bf16_t* g, bf16_t* l) {
    __builtin_amdgcn_global_load_lds(
        (const __attribute__((address_space(1))) uint32_t*)g,
        (__attribute__((address_space(3))) uint32_t*)l, 16, 0, 0);
}

// ---------------- fp32 -> bf16 convert (weights) ----------------
__global__ __launch_bounds__(256) void cvt_kernel(const float* __restrict__ in,
                                                  bf16_t* __restrict__ out) {
    int i = (blockIdx.x * 256 + threadIdx.x) * 8;
    *(bf16x8*)(out + i) = cvt8(in + i);
}

// fused Q/K/V input convert: blockIdx.y selects source
__global__ __launch_bounds__(256) void cvt3_kernel(const float* __restrict__ a,
                                                   const float* __restrict__ b,
                                                   const float* __restrict__ c,
                                                   bf16_t* __restrict__ out) {
    const float* src = blockIdx.y == 0 ? a : (blockIdx.y == 1 ? b : c);
    size_t i = ((size_t)blockIdx.x * 256 + threadIdx.x) * 8;
    *(bf16x8*)(out + (size_t)blockIdx.y * ((size_t)MROWS * DMODEL) + i) = cvt8(src + i);
}

// ---------------- mask bit-pack ----------------
__global__ __launch_bounds__(256) void pack_mask_kernel(const int* __restrict__ mask,
                                                        unsigned long long* __restrict__ bits) {
    size_t idx = (size_t)blockIdx.x * 256 + threadIdx.x;
    int v = mask[idx];
    unsigned long long b = __ballot(v != 0);
    if ((threadIdx.x & 63) == 0) bits[idx >> 6] = b;
}

// ---------------- LDS-staged GEMM: Y = X @ W^T + bias ----------------
// TM x 128 tile, BK=32, dbuf LDS, global_load_lds width-16 staging.
// batched=1: blockIdx.z in {0,1,2} selects X/W/Y slice (contiguous, stride NE/WN),
//            mode = z==2 ? 1 : 0.   batched=0: single GEMM, mode 2.
// mode 0: (B,H,S,64)  mode 1: (B,H,64,S)  mode 2: plain (M,1024)
template <int TM>
__global__ __launch_bounds__(256) void gemm_bt(
    const bf16_t* __restrict__ Xb, const bf16_t* __restrict__ Wb,
    const float* __restrict__ bq_, const float* __restrict__ bk_,
    const float* __restrict__ bv_, bf16_t* __restrict__ Yb, int batched)
{
    constexpr int WM = TM / 2;      // wave tile rows
    constexpr int MF = WM / 16;     // m-fragments per wave
    __shared__ bf16_t As[2][TM * 32];
    __shared__ bf16_t Bs[2][128 * 32];
    const int K = DMODEL;
    int lane = threadIdx.x & 63;
    int wave = threadIdx.x >> 6;
    int lr = lane & 15, lg = lane >> 4;
    int wr = wave >> 1, wc = wave & 1;
    int i0 = blockIdx.x * TM;
    int j0 = blockIdx.y * 128;

    int z = batched ? blockIdx.z : 0;
    const bf16_t* X = Xb + (size_t)z * ((size_t)MROWS * DMODEL);
    const bf16_t* W = Wb + (size_t)z * ((size_t)DMODEL * DMODEL);
    const float* bias = (z == 0) ? bq_ : (z == 1 ? bk_ : bv_);
    bf16_t* Y = Yb + (size_t)z * ((size_t)MROWS * DMODEL);
    int mode = batched ? (z == 2 ? 1 : 0) : 2;

    const bf16_t* xg = X + (size_t)(i0 + wave * 16 + (lane >> 2)) * K + (lane & 3) * 8;
    const bf16_t* wg = W + (size_t)(j0 + wave * 16 + (lane >> 2)) * K + (lane & 3) * 8;

    f32x4 acc[MF][4] = {};

    auto stage = [&](int buf, int k0) {
        #pragma unroll
        for (int r = 0; r < TM / 64; ++r)
            gl_lds16(xg + (size_t)(r * 64) * K + k0, &As[buf][r * 2048 + wave * 512]);
        #pragma unroll
        for (int r = 0; r < 2; ++r)
            gl_lds16(wg + (size_t)(r * 64) * K + k0, &Bs[buf][r * 2048 + wave * 512]);
    };

    stage(0, 0);
    for (int t = 0; t < K / 32; ++t) {
        __syncthreads();
        if (t + 1 < K / 32) stage((t + 1) & 1, (t + 1) * 32);
        const bf16_t* ab = &As[t & 1][(wr * WM + lr) * 32 + lg * 8];
        const bf16_t* bb = &Bs[t & 1][(wc * 64 + lr) * 32 + lg * 8];
        bf16x8 a[MF], b[4];
        #pragma unroll
        for (int m = 0; m < MF; ++m) a[m] = ld8(ab + m * 16 * 32);
        #pragma unroll
        for (int n = 0; n < 4; ++n) b[n] = ld8(bb + n * 16 * 32);
        __builtin_amdgcn_s_setprio(1);
        #pragma unroll
        for (int m = 0; m < MF; ++m)
            #pragma unroll
            for (int n = 0; n < 4; ++n)
                acc[m][n] = __builtin_amdgcn_mfma_f32_16x16x32_bf16(a[m], b[n], acc[m][n], 0, 0, 0);
        __builtin_amdgcn_s_setprio(0);
    }

    #pragma unroll
    for (int n = 0; n < 4; ++n) {
        int col = j0 + wc * 64 + n * 16 + lr;
        float bv = bias[col];
        #pragma unroll
        for (int m = 0; m < MF; ++m) {
            #pragma unroll
            for (int r = 0; r < 4; ++r) {
                int row = i0 + wr * WM + m * 16 + lg * 4 + r;
                float v = acc[m][n][r] + bv;
                size_t off;
                if (mode == 2) {
                    off = (size_t)row * DMODEL + col;
                } else {
                    int b_ = row >> 11, s = row & (S_LEN - 1);
                    int h = col >> 6, d = col & (DK - 1);
                    if (mode == 0) off = ((size_t)(b_ * NHEADS + h) * S_LEN + s) * DK + d;
                    else           off = ((size_t)(b_ * NHEADS + h) * DK + d) * S_LEN + s;
                }
                Y[off] = (bf16_t)v;
            }
        }
    }
}

// ---------------- fused attention ----------------
// pass 1 uses swapped QK^T (mfma(K,Q)) so each lane owns a full query row:
// row max/sum are in-lane trees + 2 shfl_xor, 1 mask word per tile.
__global__ __launch_bounds__(256) void attn_kernel(
    const bf16_t* __restrict__ qb, const bf16_t* __restrict__ kb,
    const bf16_t* __restrict__ vT, const unsigned long long* __restrict__ mbits,
    float* __restrict__ attn_out, bf16_t* __restrict__ ctx_out)
{
    __shared__ __align__(16) float psharef[4][16][68];
    int lane = threadIdx.x & 63;
    int wave = threadIdx.x >> 6;
    int lr = lane & 15, lg = lane >> 4;
    int bh = blockIdx.x >> 5;
    int b = bh >> 4, h = bh & (NHEADS - 1);
    int q0 = (blockIdx.x & 31) * 64 + wave * 16;

    const bf16_t* qp = qb + ((size_t)bh * S_LEN + q0 + lr) * DK + lg * 8;
    bf16x8 aq0 = ld8(qp), aq1 = ld8(qp + 32);

    const bf16_t* kp = kb + ((size_t)bh * S_LEN + lr) * DK + lg * 8;

    // ---- pass 1 (swapped): lane owns q-row q0+lr, keys nt*16+lg*4+r ----
    const unsigned long long* mq = mbits + ((size_t)b * S_LEN + q0 + lr) * (S_LEN / 64);
    float m_l = -1e30f, l_l = 0.f;
    for (int n0 = 0; n0 < S_LEN; n0 += 64) {
        unsigned long long mw = mq[n0 >> 6];
        f32x4 sc[4];
        __builtin_amdgcn_s_setprio(1);
        #pragma unroll
        for (int nt = 0; nt < 4; ++nt) {
            const bf16_t* kr = kp + (size_t)(n0 + nt * 16) * DK;
            f32x4 c = {0.f, 0.f, 0.f, 0.f};
            c = __builtin_amdgcn_mfma_f32_16x16x32_bf16(ld8(kr), aq0, c, 0, 0, 0);
            c = __builtin_amdgcn_mfma_f32_16x16x32_bf16(ld8(kr + 32), aq1, c, 0, 0, 0);
            sc[nt] = c;
        }
        __builtin_amdgcn_s_setprio(0);
        float sv[16];
        float mx = -1e30f;
        #pragma unroll
        for (int nt = 0; nt < 4; ++nt)
            #pragma unroll
            for (int r = 0; r < 4; ++r) {
                float s = sc[nt][r] * 0.125f;
                if (!((mw >> (nt * 16 + lg * 4 + r)) & 1ULL)) s = -1e9f;
                sv[nt * 4 + r] = s;
                mx = fmaxf(mx, s);
            }
        mx = fmaxf(mx, __shfl_xor(mx, 16, 64));
        mx = fmaxf(mx, __shfl_xor(mx, 32, 64));
        float mn = fmaxf(m_l, mx);
        float sum = 0.f;
        #pragma unroll
        for (int i = 0; i < 16; ++i) sum += __expf(sv[i] - mn);
        sum += __shfl_xor(sum, 16, 64);
        sum += __shfl_xor(sum, 32, 64);
        l_l = l_l * __expf(m_l - mn) + sum;
        m_l = mn;
    }
    // broadcast to pass-2 layout: lane (lr,lg) needs rows lg*4+r
    float m2[4], invl[4];
    #pragma unroll
    for (int r = 0; r < 4; ++r) {
        m2[r]   = __shfl(m_l, lg * 4 + r, 64);
        invl[r] = 1.f / __shfl(l_l, lg * 4 + r, 64);
    }

    // ---- pass 2: recompute scores (orig layout), write attn, accumulate P@V ----
    const unsigned long long* mp = mbits + ((size_t)b * S_LEN + q0 + lg * 4) * (S_LEN / 64);
    f32x4 ctx[4] = {};
    size_t attn_base = ((size_t)bh * S_LEN + q0) * S_LEN;
    for (int n0 = 0; n0 < S_LEN; n0 += 64) {
        int w = n0 >> 6;
        #pragma unroll
        for (int nt = 0; nt < 4; ++nt) {
            const bf16_t* kr = kp + (size_t)(n0 + nt * 16) * DK;
            f32x4 c = {0.f, 0.f, 0.f, 0.f};
            __builtin_amdgcn_s_setprio(1);
            c = __builtin_amdgcn_mfma_f32_16x16x32_bf16(aq0, ld8(kr), c, 0, 0, 0);
            c = __builtin_amdgcn_mfma_f32_16x16x32_bf16(aq1, ld8(kr + 32), c, 0, 0, 0);
            __builtin_amdgcn_s_setprio(0);
            #pragma unroll
            for (int r = 0; r < 4; ++r) {
                unsigned long long mw = mp[r * (S_LEN / 64) + w];
                float s = c[r] * 0.125f;
                if (!((mw >> (nt * 16 + lr)) & 1ULL)) s = -1e9f;
                float p = __expf(s - m2[r]) * invl[r];
                psharef[wave][lg * 4 + r][nt * 16 + lr] = p;
            }
        }
        #pragma unroll
        for (int j = 0; j < 4; ++j) {
            int flat = j * 64 + lane;
            int rr = flat >> 4, cc = (flat & 15) * 4;
            *(f32x4*)(attn_out + attn_base + (size_t)rr * S_LEN + n0 + cc) =
                *(const f32x4*)&psharef[wave][rr][cc];
        }
        #pragma unroll
        for (int t = 0; t < 2; ++t) {
            bf16x8 ap = cvt8(&psharef[wave][lr][t * 32 + lg * 8]);
            __builtin_amdgcn_s_setprio(1);
            #pragma unroll
            for (int dt = 0; dt < 4; ++dt) {
                const bf16_t* vr = vT + ((size_t)bh * DK + dt * 16 + lr) * S_LEN + n0 + t * 32 + lg * 8;
                ctx[dt] = __builtin_amdgcn_mfma_f32_16x16x32_bf16(ap, ld8(vr), ctx[dt], 0, 0, 0);
            }
            __builtin_amdgcn_s_setprio(0);
        }
    }
    #pragma unroll
    for (int dt = 0; dt < 4; ++dt) {
        #pragma unroll
        for (int r = 0; r < 4; ++r) {
            size_t row = (size_t)b * S_LEN + q0 + lg * 4 + r;
            int col = h * DK + dt * 16 + lr;
            ctx_out[row * DMODEL + col] = (bf16_t)ctx[dt][r];
        }
    }
}

// ---------------- residual + LayerNorm ----------------
__global__ __launch_bounds__(256) void ln_kernel(
    const bf16_t* __restrict__ proj, const float* __restrict__ Qres,
    const float* __restrict__ gamma, const float* __restrict__ beta,
    float* __restrict__ y)
{
    __shared__ float red[8];
    int row = blockIdx.x;
    int tid = threadIdx.x;
    int lane = tid & 63, wave = tid >> 6;
    const bf16_t* pr = proj + (size_t)row * DMODEL;
    const float*  qr = Qres + (size_t)row * DMODEL;
    float x[4];
    float sum = 0.f, sumsq = 0.f;
    #pragma unroll
    for (int i = 0; i < 4; ++i) {
        int c = tid + i * 256;
        float v = (float)pr[c] + qr[c];
        x[i] = v; sum += v; sumsq += v * v;
    }
    #pragma unroll
    for (int off = 1; off < 64; off <<= 1) {
        sum += __shfl_xor(sum, off, 64);
        sumsq += __shfl_xor(sumsq, off, 64);
    }
    if (lane == 0) { red[wave] = sum; red[4 + wave] = sumsq; }
    __syncthreads();
    sum = red[0] + red[1] + red[2] + red[3];
    sumsq = red[4] + red[5] + red[6] + red[7];
    float mu = sum * (1.f / DMODEL);
    float var = sumsq * (1.f / DMODEL) - mu * mu;
    float rstd = rsqrtf(var + 1e-5f);
    #pragma unroll
    for (int i = 0; i < 4; ++i) {
        int c = tid + i * 256;
        y[(size_t)row * DMODEL + c] = (x[i] - mu) * rstd * gamma[c] + beta[c];
    }
}

extern "C" void kernel_launch(void* const* d_in, const int* in_sizes, int n_in,
                              void* d_out, int out_size, void* d_ws, size_t ws_size,
                              hipStream_t stream) {
    (void)in_sizes; (void)n_in; (void)out_size; (void)ws_size;
    const float* Q   = (const float*)d_in[0];
    const float* Kin = (const float*)d_in[1];
    const float* Vin = (const float*)d_in[2];
    const int*   mask= (const int*)d_in[3];
    const float* Wq  = (const float*)d_in[4];
    const float* bq  = (const float*)d_in[5];
    const float* Wk  = (const float*)d_in[6];
    const float* bk  = (const float*)d_in[7];
    const float* Wv  = (const float*)d_in[8];
    const float* bv  = (const float*)d_in[9];
    const float* Wo  = (const float*)d_in[10];
    const float* bo  = (const float*)d_in[11];
    const float* lng = (const float*)d_in[12];
    const float* lnb = (const float*)d_in[13];

    const size_t NE = (size_t)BATCH * S_LEN * DMODEL;   // 8,388,608
    const size_t WN = (size_t)DMODEL * DMODEL;          // 1,048,576
    bf16_t* wqb  = (bf16_t*)d_ws;          // wq,wk,wv,wo bf16 (contiguous)
    bf16_t* wkb  = wqb + WN;
    bf16_t* wvb  = wkb + WN;
    bf16_t* wob  = wvb + WN;
    bf16_t* qbuf = wob + WN;               // q,k,vT bf16 (contiguous, stride NE)
    bf16_t* kbuf = qbuf + NE;
    bf16_t* vtbuf= kbuf + NE;
    bf16_t* ctxbuf = vtbuf + NE;           // (B,S,1024)
    bf16_t* outbuf = qbuf;                 // reuse: qbuf dead after attn
    unsigned long long* mbits = (unsigned long long*)(ctxbuf + NE);  // (B,S,S/64)

    float* y_out    = (float*)d_out;
    float* attn_out = y_out + NE;
    // bf16 input scratch lives in the (later-overwritten) attn_out region: 48MB << 1.07GB
    bf16_t* x16 = (bf16_t*)attn_out;

    cvt_kernel<<<WN / 2048, 256, 0, stream>>>(Wq, wqb);
    cvt_kernel<<<WN / 2048, 256, 0, stream>>>(Wk, wkb);
    cvt_kernel<<<WN / 2048, 256, 0, stream>>>(Wv, wvb);
    cvt_kernel<<<WN / 2048, 256, 0, stream>>>(Wo, wob);

    const int mask_elems = BATCH * S_LEN * S_LEN;       // 16,777,216
    pack_mask_kernel<<<mask_elems / 256, 256, 0, stream>>>(mask, mbits);

    cvt3_kernel<<<dim3(NE / 2048, 3), 256, 0, stream>>>(Q, Kin, Vin, x16);

    // batched Q/K/V projection: 1536 blocks (5 blocks/CU, LDS 32KB)
    gemm_bt<128><<<dim3(MROWS / 128, DMODEL / 128, 3), 256, 0, stream>>>(
        x16, wqb, bq, bk, bv, qbuf, 1);

    attn_kernel<<<BATCH * NHEADS * (S_LEN / 64), 256, 0, stream>>>(
        qbuf, kbuf, vtbuf, mbits, attn_out, ctxbuf);

    // output projection: 64x128 tile -> 1024 blocks
    gemm_bt<64><<<dim3(MROWS / 64, DMODEL / 128), 256, 0, stream>>>(
        ctxbuf, wob, bo, bo, bo, outbuf, 0);

    ln_kernel<<<BATCH * S_LEN, 256, 0, stream>>>(outbuf, Q, lng, lnb, y_out);
}